// Round 1
// baseline (6622.206 us; speedup 1.0000x reference)
//
#include <hip/hip_runtime.h>
#include <math.h>

#define DM    1024
#define NH    16
#define DH    64
#define DI    4096
#define QL    1024
#define MLN   1024
#define BATCH 2
#define KL    2048   // QL + MLN

typedef unsigned short u16;
typedef short s16x8 __attribute__((ext_vector_type(8)));
typedef float f32x4 __attribute__((ext_vector_type(4)));

__device__ __forceinline__ u16 f2bf(float f) {
    union { float f; unsigned u; } v; v.f = f;
    unsigned u = v.u;
    unsigned r = (u + 0x7FFFu + ((u >> 16) & 1u)) >> 16;
    return (u16)r;
}
__device__ __forceinline__ float bf2f(u16 h) {
    union { unsigned u; float f; } v; v.u = ((unsigned)h) << 16;
    return v.f;
}

// ---------------- fp32 -> bf16 convert ----------------
__global__ __launch_bounds__(256) void cvt_f2b(const float* __restrict__ x,
                                               u16* __restrict__ y, int n) {
    int i = blockIdx.x * 256 + threadIdx.x;
    int stride = gridDim.x * 256;
    for (; i < n; i += stride) y[i] = f2bf(x[i]);
}

// ---------------- GEMM: C[M,N] = A[M,K] * B[N,K]^T ----------------
// FLAGS: 1 = bf16 out, 2 = add bias, 4 = relu
template <int FLAGS>
__global__ __launch_bounds__(256) void gemm_bt(const u16* __restrict__ A,
                                               const u16* __restrict__ B,
                                               float* __restrict__ Cf,
                                               u16* __restrict__ Cb,
                                               const float* __restrict__ bias,
                                               int M, int N, int K) {
    const int lane = threadIdx.x & 63;
    const int wid  = threadIdx.x >> 6;        // 0..3
    const int wm = wid >> 1, wn = wid & 1;    // 2x2 wave grid
    const int m_base = blockIdx.y * 128 + wm * 64;
    const int n_base = blockIdx.x * 128 + wn * 64;
    const int lr   = lane & 15;
    const int quad = lane >> 4;

    f32x4 acc[4][4];
#pragma unroll
    for (int i = 0; i < 4; ++i)
#pragma unroll
        for (int j = 0; j < 4; ++j) acc[i][j] = (f32x4)0.0f;

    for (int k0 = 0; k0 < K; k0 += 32) {
        s16x8 a[4], b[4];
#pragma unroll
        for (int t = 0; t < 4; ++t) {
            a[t] = *reinterpret_cast<const s16x8*>(
                A + (size_t)(m_base + t * 16 + lr) * K + k0 + quad * 8);
            b[t] = *reinterpret_cast<const s16x8*>(
                B + (size_t)(n_base + t * 16 + lr) * K + k0 + quad * 8);
        }
#pragma unroll
        for (int i = 0; i < 4; ++i)
#pragma unroll
            for (int j = 0; j < 4; ++j)
                acc[i][j] = __builtin_amdgcn_mfma_f32_16x16x32_bf16(
                    a[i], b[j], acc[i][j], 0, 0, 0);
    }

#pragma unroll
    for (int i = 0; i < 4; ++i) {
#pragma unroll
        for (int j = 0; j < 4; ++j) {
            int row0 = m_base + i * 16 + quad * 4;
            int col  = n_base + j * 16 + lr;
            float bv = (FLAGS & 2) ? bias[col] : 0.0f;
#pragma unroll
            for (int r = 0; r < 4; ++r) {
                float v = acc[i][j][r] + bv;
                if (FLAGS & 4) v = fmaxf(v, 0.0f);
                size_t idx = (size_t)(row0 + r) * N + col;
                if (FLAGS & 1) Cb[idx] = f2bf(v);
                else           Cf[idx] = v;
            }
        }
    }
}

// ---------------- fused rel-attention ----------------
// One block per (i, b*16+n). Wh holds [q|k|v] rows m = kpos*2+b, cols e in [0,3072).
__global__ __launch_bounds__(256) void attn_fused(
    const u16* __restrict__ Wh, const float* __restrict__ r_emb,
    const float* __restrict__ r_w_bias, const float* __restrict__ r_bias,
    u16* __restrict__ av) {
    const int i  = blockIdx.x;
    const int bn = blockIdx.y;
    const int b  = bn >> 4;
    const int n  = bn & 15;
    const int t = threadIdx.x, lane = t & 63, wv = t >> 6;

    __shared__ float q_s[64], qw_s[64];
    __shared__ float sc[KL];
    __shared__ float red[8];
    __shared__ float pred[256];

    if (t < 64) {
        float qv = bf2f(Wh[(size_t)((QL + i) * 2 + b) * 3072 + n * 64 + t]);
        q_s[t]  = qv;
        qw_s[t] = qv + r_w_bias[n * 64 + t];
    }
    __syncthreads();

    const int jmax = i + MLN;           // last unmasked j
    const int joff = QL - 1 - i;        // rel-shift offset: jj = j + joff
    const float scale = 0.125f;

    {
        const float qd = q_s[lane], qwd = qw_s[lane];
        for (int s = 0; s < KL / 4; ++s) {
            int j = s * 4 + wv;
            float p = 0.0f;
            if (j <= jmax) {
                float kvv = bf2f(Wh[(size_t)(j * 2 + b) * 3072 + 1024 + n * 64 + lane]);
                float rv  = r_emb[(size_t)(j + joff) * (NH * DH) + n * 64 + lane];
                p = qwd * kvv + qd * rv;
            }
#pragma unroll
            for (int o = 32; o; o >>= 1) p += __shfl_xor(p, o, 64);
            if (lane == 0)
                sc[j] = (j <= jmax)
                            ? (p + r_bias[(size_t)(j + joff) * NH + n]) * scale
                            : -INFINITY;
        }
    }
    __syncthreads();

    // softmax: max
    float mx = -INFINITY;
    for (int j = t; j < KL; j += 256) mx = fmaxf(mx, sc[j]);
#pragma unroll
    for (int o = 32; o; o >>= 1) mx = fmaxf(mx, __shfl_xor(mx, o, 64));
    if (lane == 0) red[wv] = mx;
    __syncthreads();
    mx = fmaxf(fmaxf(red[0], red[1]), fmaxf(red[2], red[3]));

    float sm = 0.0f;
    for (int j = t; j < KL; j += 256) {
        float e = __expf(sc[j] - mx);
        sc[j] = e;
        sm += e;
    }
#pragma unroll
    for (int o = 32; o; o >>= 1) sm += __shfl_xor(sm, o, 64);
    if (lane == 0) red[4 + wv] = sm;
    __syncthreads();
    float rinv = 1.0f / (red[4] + red[5] + red[6] + red[7]);

    // PV
    const int d = t & 63, g = t >> 6;
    float accv = 0.0f;
    int j0 = g * 512;
    int j1 = j0 + 512 < jmax + 1 ? j0 + 512 : jmax + 1;
    for (int j = j0; j < j1; ++j)
        accv += sc[j] * bf2f(Wh[(size_t)(j * 2 + b) * 3072 + 2048 + n * 64 + d]);
    pred[t] = accv;
    __syncthreads();
    if (t < 64) {
        float o = (pred[t] + pred[t + 64] + pred[t + 128] + pred[t + 192]) * rinv;
        av[(size_t)(i * 2 + b) * (NH * DH) + n * 64 + t] = f2bf(o);
    }
}

// ---------------- fused residual + LayerNorm ----------------
// mode: 1 = write fp32, 2 = write bf16 (can be both)
__global__ __launch_bounds__(256) void ln_fused(
    const float* __restrict__ x1, const float* __restrict__ x2,
    const float* __restrict__ gw, const float* __restrict__ bw,
    float* __restrict__ outf, u16* __restrict__ outb, int mode) {
    const int row = blockIdx.x, t = threadIdx.x, lane = t & 63, wv = t >> 6;
    __shared__ float red[8];
    float x[4];
    float s = 0.0f, s2 = 0.0f;
#pragma unroll
    for (int r = 0; r < 4; ++r) {
        int c = t + r * 256;
        float v = x1[(size_t)row * DM + c] + x2[(size_t)row * DM + c];
        x[r] = v;
        s += v;
        s2 += v * v;
    }
#pragma unroll
    for (int o = 32; o; o >>= 1) {
        s  += __shfl_xor(s, o, 64);
        s2 += __shfl_xor(s2, o, 64);
    }
    if (lane == 0) { red[wv] = s; red[4 + wv] = s2; }
    __syncthreads();
    s  = red[0] + red[1] + red[2] + red[3];
    s2 = red[4] + red[5] + red[6] + red[7];
    float mean = s * (1.0f / DM);
    float var  = s2 * (1.0f / DM) - mean * mean;
    float rstd = rsqrtf(var + 1e-5f);
#pragma unroll
    for (int r = 0; r < 4; ++r) {
        int c = t + r * 256;
        float y = gw[c] * (x[r] - mean) * rstd + bw[c];
        size_t idx = (size_t)row * DM + c;
        if (mode & 1) outf[idx] = y;
        if (mode & 2) outb[idx] = f2bf(y);
    }
}

extern "C" void kernel_launch(void* const* d_in, const int* in_sizes, int n_in,
                              void* d_out, int out_size, void* d_ws, size_t ws_size,
                              hipStream_t stream) {
    const float* w        = (const float*)d_in[0];
    const float* mems     = (const float*)d_in[1];
    const float* r_emb    = (const float*)d_in[2];
    const float* r_w_bias = (const float*)d_in[3];
    const float* r_bias   = (const float*)d_in[4];
    const float* qkv_w    = (const float*)d_in[5];
    const float* o_w      = (const float*)d_in[6];
    const float* ln1_g    = (const float*)d_in[7];
    const float* ln1_b    = (const float*)d_in[8];
    const float* ff_w1    = (const float*)d_in[9];
    const float* ff_b1    = (const float*)d_in[10];
    const float* ff_w2    = (const float*)d_in[11];
    const float* ff_b2    = (const float*)d_in[12];
    const float* ln2_g    = (const float*)d_in[13];
    const float* ln2_b    = (const float*)d_in[14];
    float* out = (float*)d_out;

    char* ws = (char*)d_ws;
    size_t off = 0;
    auto alloc = [&](size_t bytes) {
        size_t o = off;
        off += (bytes + 255) & ~(size_t)255;
        return o;
    };
    u16* cat_bf   = (u16*)(ws + alloc((size_t)KL * BATCH * DM * 2));      // 8 MB
    u16* qkvw_bf  = (u16*)(ws + alloc((size_t)3 * NH * DH * DM * 2));     // 6 MB
    u16* ow_bf    = (u16*)(ws + alloc((size_t)DM * NH * DH * 2));         // 2 MB
    u16* w1_bf    = (u16*)(ws + alloc((size_t)DI * DM * 2));              // 8 MB
    u16* w2_bf    = (u16*)(ws + alloc((size_t)DM * DI * 2));              // 8 MB
    u16* Wh_bf    = (u16*)(ws + alloc((size_t)KL * BATCH * 3072 * 2));    // 24 MB
    u16* av_bf    = (u16*)(ws + alloc((size_t)QL * BATCH * DM * 2));      // 4 MB
    float* ao_f   = (float*)(ws + alloc((size_t)QL * BATCH * DM * 4));    // 8 MB
    float* h_f    = (float*)(ws + alloc((size_t)QL * BATCH * DM * 4));    // 8 MB
    u16* h_bf     = (u16*)(ws + alloc((size_t)QL * BATCH * DM * 2));      // 4 MB
    u16* inner_bf = (u16*)(ws + alloc((size_t)QL * BATCH * DI * 2));      // 16 MB
    float* ffo_f  = (float*)(ws + alloc((size_t)QL * BATCH * DM * 4));    // 8 MB
    (void)ws_size; (void)in_sizes; (void)n_in; (void)out_size;

    // 1) fp32 -> bf16 conversions (cat = [mems; w])
    cvt_f2b<<<1024, 256, 0, stream>>>(mems, cat_bf, MLN * BATCH * DM);
    cvt_f2b<<<1024, 256, 0, stream>>>(w, cat_bf + (size_t)MLN * BATCH * DM, QL * BATCH * DM);
    cvt_f2b<<<1024, 256, 0, stream>>>(qkv_w, qkvw_bf, 3 * NH * DH * DM);
    cvt_f2b<<<512, 256, 0, stream>>>(o_w, ow_bf, DM * NH * DH);
    cvt_f2b<<<1024, 256, 0, stream>>>(ff_w1, w1_bf, DI * DM);
    cvt_f2b<<<1024, 256, 0, stream>>>(ff_w2, w2_bf, DM * DI);

    // 2) QKV projection: (4096 x 3072) = cat (4096 x 1024) * qkv_w^T
    gemm_bt<1><<<dim3(3072 / 128, (KL * BATCH) / 128), 256, 0, stream>>>(
        cat_bf, qkvw_bf, nullptr, Wh_bf, nullptr, KL * BATCH, 3072, DM);

    // 3) fused attention
    attn_fused<<<dim3(QL, BATCH * NH), 256, 0, stream>>>(Wh_bf, r_emb, r_w_bias,
                                                         r_bias, av_bf);

    // 4) output projection: (2048 x 1024) = av (2048 x 1024) * o_w^T
    gemm_bt<0><<<dim3(DM / 128, (QL * BATCH) / 128), 256, 0, stream>>>(
        av_bf, ow_bf, ao_f, nullptr, nullptr, QL * BATCH, DM, DM);

    // 5) h = LN(w + attn_out)  -> fp32 (residual) + bf16 (gemm input)
    ln_fused<<<QL * BATCH, 256, 0, stream>>>(w, ao_f, ln1_g, ln1_b, h_f, h_bf, 3);

    // 6) inner = relu(h * ff_w1^T + b1)
    gemm_bt<1 | 2 | 4><<<dim3(DI / 128, (QL * BATCH) / 128), 256, 0, stream>>>(
        h_bf, w1_bf, nullptr, inner_bf, ff_b1, QL * BATCH, DI, DM);

    // 7) ff_out = inner * ff_w2^T + b2
    gemm_bt<2><<<dim3(DM / 128, (QL * BATCH) / 128), 256, 0, stream>>>(
        inner_bf, w2_bf, ffo_f, nullptr, ff_b2, QL * BATCH, DM, DI);

    // 8) out = LN(h + ff_out)
    ln_fused<<<QL * BATCH, 256, 0, stream>>>(h_f, ffo_f, ln2_g, ln2_b, out, nullptr, 1);
}

// Round 2
// 751.810 us; speedup vs baseline: 8.8084x; 8.8084x over previous
//
#include <hip/hip_runtime.h>
#include <math.h>

#define DM    1024
#define NH    16
#define DH    64
#define DI    4096
#define QL    1024
#define MLN   1024
#define BATCH 2
#define KL    2048   // QL + MLN

typedef unsigned short u16;
typedef short s16x8 __attribute__((ext_vector_type(8)));
typedef float f32x4 __attribute__((ext_vector_type(4)));

__device__ __forceinline__ u16 f2bf(float f) {
    union { float f; unsigned u; } v; v.f = f;
    unsigned u = v.u;
    unsigned r = (u + 0x7FFFu + ((u >> 16) & 1u)) >> 16;
    return (u16)r;
}
__device__ __forceinline__ float bf2f(u16 h) {
    union { unsigned u; float f; } v; v.u = ((unsigned)h) << 16;
    return v.f;
}

// ---------------- fp32 -> bf16 convert ----------------
__global__ __launch_bounds__(256) void cvt_f2b(const float* __restrict__ x,
                                               u16* __restrict__ y, int n) {
    int i = blockIdx.x * 256 + threadIdx.x;
    int stride = gridDim.x * 256;
    for (; i < n; i += stride) y[i] = f2bf(x[i]);
}

// rb2[n][jj] = 0.125*(r_bias[jj,n] - r_w_bias[n,:].dot(r_emb[jj,n,:]))
__global__ __launch_bounds__(256) void rb2_prep(const float* __restrict__ r_emb,
                                                const float* __restrict__ r_w_bias,
                                                const float* __restrict__ r_bias,
                                                float* __restrict__ rb2) {
    int id = blockIdx.x * 256 + threadIdx.x;
    if (id >= NH * KL) return;
    int n = id >> 11, jj = id & (KL - 1);
    float dot = 0.0f;
#pragma unroll 8
    for (int d = 0; d < 64; ++d)
        dot += r_w_bias[n * 64 + d] * r_emb[(size_t)jj * (NH * DH) + n * 64 + d];
    rb2[n * KL + jj] = 0.125f * (r_bias[jj * NH + n] - dot);
}

// ---------------- GEMM: C[M,N] = A[M,K] * B[N,K]^T ----------------
// FLAGS: 1 = bf16 out, 2 = add bias, 4 = relu
template <int FLAGS>
__global__ __launch_bounds__(256) void gemm_bt(const u16* __restrict__ A,
                                               const u16* __restrict__ B,
                                               float* __restrict__ Cf,
                                               u16* __restrict__ Cb,
                                               const float* __restrict__ bias,
                                               int M, int N, int K) {
    const int lane = threadIdx.x & 63;
    const int wid  = threadIdx.x >> 6;
    const int wm = wid >> 1, wn = wid & 1;
    const int m_base = blockIdx.y * 128 + wm * 64;
    const int n_base = blockIdx.x * 128 + wn * 64;
    const int lr   = lane & 15;
    const int quad = lane >> 4;

    f32x4 acc[4][4];
#pragma unroll
    for (int i = 0; i < 4; ++i)
#pragma unroll
        for (int j = 0; j < 4; ++j) acc[i][j] = (f32x4)0.0f;

    for (int k0 = 0; k0 < K; k0 += 32) {
        s16x8 a[4], b[4];
#pragma unroll
        for (int t = 0; t < 4; ++t) {
            a[t] = *reinterpret_cast<const s16x8*>(
                A + (size_t)(m_base + t * 16 + lr) * K + k0 + quad * 8);
            b[t] = *reinterpret_cast<const s16x8*>(
                B + (size_t)(n_base + t * 16 + lr) * K + k0 + quad * 8);
        }
#pragma unroll
        for (int i = 0; i < 4; ++i)
#pragma unroll
            for (int j = 0; j < 4; ++j)
                acc[i][j] = __builtin_amdgcn_mfma_f32_16x16x32_bf16(
                    a[i], b[j], acc[i][j], 0, 0, 0);
    }

#pragma unroll
    for (int i = 0; i < 4; ++i) {
#pragma unroll
        for (int j = 0; j < 4; ++j) {
            int row0 = m_base + i * 16 + quad * 4;
            int col  = n_base + j * 16 + lr;
            float bv = (FLAGS & 2) ? bias[col] : 0.0f;
#pragma unroll
            for (int r = 0; r < 4; ++r) {
                float v = acc[i][j][r] + bv;
                if (FLAGS & 4) v = fmaxf(v, 0.0f);
                size_t idx = (size_t)(row0 + r) * N + col;
                if (FLAGS & 1) Cb[idx] = f2bf(v);
                else           Cf[idx] = v;
            }
        }
    }
}

// ---------------- flash attention with rel-pos via inline Bt MFMA ----------------
// Block: 64 Q-rows (i0..i0+63) for one (b,n). 4 waves, wave w owns j-cols
// [w*32, w*32+32) of each 128-wide macro-tile; per-wave online softmax state,
// merged at the end through LDS.
__global__ __launch_bounds__(256, 2) void flash_attn(
    const u16* __restrict__ Wh, const u16* __restrict__ r_bf,
    const float* __restrict__ r_w_bias, const float* __restrict__ rb2,
    u16* __restrict__ av) {
    const int i0 = blockIdx.x * 64;
    const int bn = blockIdx.y;
    const int b = bn >> 4, n = bn & 15;
    const int t = threadIdx.x;
    const int lane = t & 63, w = t >> 6;
    const int lr = lane & 15, quad = lane >> 4;

    __shared__ char smem[65024];
    u16* Vt = (u16*)smem;                       // [64][136] V^T (d-major)
    u16* Bt = (u16*)(smem + 17408);             // [64][196] shifted-bias tile
    u16* Pw = (u16*)(smem + 42496) + w * 2560;  // [64][40] probs, per wave
    float* m_s = (float*)(smem + 62976);        // [4][64]
    float* l_s = m_s + 256;                     // [4][64]
    float* Oacc = (float*)smem;                 // [64][66], reuses Vt/Bt space

    // qw = bf16(0.125*(q + r_w_bias)); used for both S-GEMM and Bt-GEMM.
    s16x8 qw[4][2];
#pragma unroll
    for (int mt = 0; mt < 4; ++mt)
#pragma unroll
        for (int ks = 0; ks < 2; ++ks) {
            int i = i0 + mt * 16 + lr;
            const u16* qp = Wh + (size_t)((QL + i) * 2 + b) * 3072 + n * 64 + ks * 32 + quad * 8;
            s16x8 qv = *(const s16x8*)qp;
            s16x8 o;
#pragma unroll
            for (int k = 0; k < 8; ++k) {
                float f = bf2f((u16)qv[k]) + r_w_bias[n * 64 + ks * 32 + quad * 8 + k];
                o[k] = (short)f2bf(f * 0.125f);
            }
            qw[mt][ks] = o;
        }

    f32x4 O[4][4];
    float m_r[4][4], l_r[4][4];
#pragma unroll
    for (int mt = 0; mt < 4; ++mt)
#pragma unroll
        for (int x = 0; x < 4; ++x) {
            O[mt][x] = (f32x4)0.0f;
            m_r[mt][x] = -INFINITY;
            l_r[mt][x] = 0.0f;
        }

    const int jend = i0 + 64 + MLN;   // max unmasked j (exclusive, rounded to 64)
    for (int j0 = 0; j0 < jend; j0 += 128) {
        __syncthreads();   // prior iter's Vt/Bt reads complete

        // ---- stage V^T [d][j] ----
        {
            int j = t & 127, dg = t >> 7;
            const u16* vp = Wh + (size_t)((j0 + j) * 2 + b) * 3072 + 2048 + n * 64 + dg * 32;
#pragma unroll
            for (int c = 0; c < 4; ++c) {
                s16x8 vv = *(const s16x8*)(vp + c * 8);
#pragma unroll
                for (int k = 0; k < 8; ++k)
                    Vt[(dg * 32 + c * 8 + k) * 136 + j] = (u16)vv[k];
            }
        }
        // ---- Bt tile: rows i-local, cols jjloc in [0,192); wave w does 3 col-tiles ----
        const int jjbase = j0 + 960 - i0;   // jj = jjbase + jjloc; jjloc = colj + 63 - row
        {
            f32x4 bacc[4][3];
#pragma unroll
            for (int mt = 0; mt < 4; ++mt)
#pragma unroll
                for (int c = 0; c < 3; ++c) bacc[mt][c] = (f32x4)0.0f;
#pragma unroll
            for (int ks = 0; ks < 2; ++ks) {
                s16x8 rf[3];
#pragma unroll
                for (int c = 0; c < 3; ++c) {
                    int jj = jjbase + (w * 3 + c) * 16 + lr;
                    jj = jj < 0 ? 0 : (jj > KL - 1 ? KL - 1 : jj);
                    rf[c] = *(const s16x8*)(r_bf + (size_t)jj * DM + n * 64 + ks * 32 + quad * 8);
                }
#pragma unroll
                for (int mt = 0; mt < 4; ++mt)
#pragma unroll
                    for (int c = 0; c < 3; ++c)
                        bacc[mt][c] = __builtin_amdgcn_mfma_f32_16x16x32_bf16(
                            qw[mt][ks], rf[c], bacc[mt][c], 0, 0, 0);
            }
            float rbv[3];
#pragma unroll
            for (int c = 0; c < 3; ++c) {
                int jj = jjbase + (w * 3 + c) * 16 + lr;
                rbv[c] = (jj >= 0 && jj < KL) ? rb2[n * KL + jj] : 0.0f;
            }
#pragma unroll
            for (int mt = 0; mt < 4; ++mt)
#pragma unroll
                for (int c = 0; c < 3; ++c) {
                    int col = (w * 3 + c) * 16 + lr;
#pragma unroll
                    for (int r = 0; r < 4; ++r) {
                        int row = mt * 16 + quad * 4 + r;
                        Bt[row * 196 + col] = f2bf(bacc[mt][c][r] + rbv[c]);
                    }
                }
        }
        __syncthreads();

        // ---- S = qw . K^T for this wave's 32 cols ----
        f32x4 sacc[4][2];
#pragma unroll
        for (int mt = 0; mt < 4; ++mt)
#pragma unroll
            for (int nt = 0; nt < 2; ++nt) sacc[mt][nt] = (f32x4)0.0f;
#pragma unroll
        for (int ks = 0; ks < 2; ++ks) {
            s16x8 kf[2];
#pragma unroll
            for (int nt = 0; nt < 2; ++nt) {
                int j = j0 + w * 32 + nt * 16 + lr;
                kf[nt] = *(const s16x8*)(Wh + (size_t)(j * 2 + b) * 3072 + 1024 + n * 64 + ks * 32 + quad * 8);
            }
#pragma unroll
            for (int mt = 0; mt < 4; ++mt)
#pragma unroll
                for (int nt = 0; nt < 2; ++nt)
                    sacc[mt][nt] = __builtin_amdgcn_mfma_f32_16x16x32_bf16(
                        qw[mt][ks], kf[nt], sacc[mt][nt], 0, 0, 0);
        }
        // ---- add shifted bias, mask (in place) ----
#pragma unroll
        for (int mt = 0; mt < 4; ++mt)
#pragma unroll
            for (int nt = 0; nt < 2; ++nt) {
                int colj = w * 32 + nt * 16 + lr;
                int j = j0 + colj;
#pragma unroll
                for (int r = 0; r < 4; ++r) {
                    int row = mt * 16 + quad * 4 + r;
                    int i = i0 + row;
                    int jjloc = colj + 63 - row;
                    float v = sacc[mt][nt][r] + bf2f(Bt[row * 196 + jjloc]);
                    sacc[mt][nt][r] = (j <= i + MLN) ? v : -INFINITY;
                }
            }
        // ---- online softmax update ----
#pragma unroll
        for (int mt = 0; mt < 4; ++mt) {
            float rmax[4], al[4], ps[4];
#pragma unroll
            for (int r = 0; r < 4; ++r) rmax[r] = fmaxf(sacc[mt][0][r], sacc[mt][1][r]);
#pragma unroll
            for (int msk = 1; msk <= 8; msk <<= 1)
#pragma unroll
                for (int r = 0; r < 4; ++r)
                    rmax[r] = fmaxf(rmax[r], __shfl_xor(rmax[r], msk, 64));
#pragma unroll
            for (int r = 0; r < 4; ++r) {
                float mo = m_r[mt][r];
                float mn = fmaxf(mo, rmax[r]);
                float a = __expf(mo - mn);
                m_r[mt][r] = mn; al[r] = a;
#pragma unroll
                for (int nt = 0; nt < 4; ++nt) O[mt][nt][r] *= a;
                float p0 = __expf(sacc[mt][0][r] - mn);
                float p1 = __expf(sacc[mt][1][r] - mn);
                ps[r] = p0 + p1;
                int row = mt * 16 + quad * 4 + r;
                Pw[row * 40 + lr]      = f2bf(p0);
                Pw[row * 40 + 16 + lr] = f2bf(p1);
            }
#pragma unroll
            for (int msk = 1; msk <= 8; msk <<= 1)
#pragma unroll
                for (int r = 0; r < 4; ++r) ps[r] += __shfl_xor(ps[r], msk, 64);
#pragma unroll
            for (int r = 0; r < 4; ++r) l_r[mt][r] = l_r[mt][r] * al[r] + ps[r];
        }
        // ---- O += P . V (per-wave, K=32) ----
        s16x8 pa[4], vb[4];
#pragma unroll
        for (int mt = 0; mt < 4; ++mt)
            pa[mt] = *(const s16x8*)(Pw + (mt * 16 + lr) * 40 + quad * 8);
#pragma unroll
        for (int nt = 0; nt < 4; ++nt)
            vb[nt] = *(const s16x8*)(Vt + (nt * 16 + lr) * 136 + w * 32 + quad * 8);
#pragma unroll
        for (int mt = 0; mt < 4; ++mt)
#pragma unroll
            for (int nt = 0; nt < 4; ++nt)
                O[mt][nt] = __builtin_amdgcn_mfma_f32_16x16x32_bf16(
                    pa[mt], vb[nt], O[mt][nt], 0, 0, 0);
    }

    // ---- merge the 4 per-wave partials ----
    __syncthreads();
    if (lr == 0) {
#pragma unroll
        for (int mt = 0; mt < 4; ++mt)
#pragma unroll
            for (int r = 0; r < 4; ++r) {
                int row = mt * 16 + quad * 4 + r;
                m_s[w * 64 + row] = m_r[mt][r];
                l_s[w * 64 + row] = l_r[mt][r];
            }
    }
    __syncthreads();
    float fw[4][4];
#pragma unroll
    for (int mt = 0; mt < 4; ++mt)
#pragma unroll
        for (int r = 0; r < 4; ++r) {
            int row = mt * 16 + quad * 4 + r;
            float M = fmaxf(fmaxf(m_s[row], m_s[64 + row]),
                            fmaxf(m_s[128 + row], m_s[192 + row]));
            fw[mt][r] = __expf(m_r[mt][r] - M);
        }
    for (int pass = 0; pass < 4; ++pass) {
        if (w == pass) {
#pragma unroll
            for (int mt = 0; mt < 4; ++mt)
#pragma unroll
                for (int nt = 0; nt < 4; ++nt) {
                    int col = nt * 16 + lr;
#pragma unroll
                    for (int r = 0; r < 4; ++r) {
                        int row = mt * 16 + quad * 4 + r;
                        float v = O[mt][nt][r] * fw[mt][r];
                        if (pass == 0) Oacc[row * 66 + col] = v;
                        else           Oacc[row * 66 + col] += v;
                    }
                }
        }
        __syncthreads();
    }
    {
        int row = t >> 2, dg = (t & 3) * 16;
        float M = fmaxf(fmaxf(m_s[row], m_s[64 + row]),
                        fmaxf(m_s[128 + row], m_s[192 + row]));
        float L = 0.0f;
#pragma unroll
        for (int wv = 0; wv < 4; ++wv)
            L += __expf(m_s[wv * 64 + row] - M) * l_s[wv * 64 + row];
        float rL = 1.0f / L;
        int i = i0 + row;
        u16* op = av + (size_t)(i * 2 + b) * DM + n * 64 + dg;
#pragma unroll
        for (int c = 0; c < 16; ++c) op[c] = f2bf(Oacc[row * 66 + dg + c] * rL);
    }
}

// ---------------- fused residual + LayerNorm ----------------
__global__ __launch_bounds__(256) void ln_fused(
    const float* __restrict__ x1, const float* __restrict__ x2,
    const float* __restrict__ gw, const float* __restrict__ bw,
    float* __restrict__ outf, u16* __restrict__ outb, int mode) {
    const int row = blockIdx.x, t = threadIdx.x, lane = t & 63, wv = t >> 6;
    __shared__ float red[8];
    float x[4];
    float s = 0.0f, s2 = 0.0f;
#pragma unroll
    for (int r = 0; r < 4; ++r) {
        int c = t + r * 256;
        float v = x1[(size_t)row * DM + c] + x2[(size_t)row * DM + c];
        x[r] = v;
        s += v;
        s2 += v * v;
    }
#pragma unroll
    for (int o = 32; o; o >>= 1) {
        s  += __shfl_xor(s, o, 64);
        s2 += __shfl_xor(s2, o, 64);
    }
    if (lane == 0) { red[wv] = s; red[4 + wv] = s2; }
    __syncthreads();
    s  = red[0] + red[1] + red[2] + red[3];
    s2 = red[4] + red[5] + red[6] + red[7];
    float mean = s * (1.0f / DM);
    float var  = s2 * (1.0f / DM) - mean * mean;
    float rstd = rsqrtf(var + 1e-5f);
#pragma unroll
    for (int r = 0; r < 4; ++r) {
        int c = t + r * 256;
        float y = gw[c] * (x[r] - mean) * rstd + bw[c];
        size_t idx = (size_t)row * DM + c;
        if (mode & 1) outf[idx] = y;
        if (mode & 2) outb[idx] = f2bf(y);
    }
}

extern "C" void kernel_launch(void* const* d_in, const int* in_sizes, int n_in,
                              void* d_out, int out_size, void* d_ws, size_t ws_size,
                              hipStream_t stream) {
    const float* w        = (const float*)d_in[0];
    const float* mems     = (const float*)d_in[1];
    const float* r_emb    = (const float*)d_in[2];
    const float* r_w_bias = (const float*)d_in[3];
    const float* r_bias   = (const float*)d_in[4];
    const float* qkv_w    = (const float*)d_in[5];
    const float* o_w      = (const float*)d_in[6];
    const float* ln1_g    = (const float*)d_in[7];
    const float* ln1_b    = (const float*)d_in[8];
    const float* ff_w1    = (const float*)d_in[9];
    const float* ff_b1    = (const float*)d_in[10];
    const float* ff_w2    = (const float*)d_in[11];
    const float* ff_b2    = (const float*)d_in[12];
    const float* ln2_g    = (const float*)d_in[13];
    const float* ln2_b    = (const float*)d_in[14];
    float* out = (float*)d_out;

    char* ws = (char*)d_ws;
    size_t off = 0;
    auto alloc = [&](size_t bytes) {
        size_t o = off;
        off += (bytes + 255) & ~(size_t)255;
        return o;
    };
    u16* cat_bf   = (u16*)(ws + alloc((size_t)KL * BATCH * DM * 2));
    u16* qkvw_bf  = (u16*)(ws + alloc((size_t)3 * NH * DH * DM * 2));
    u16* ow_bf    = (u16*)(ws + alloc((size_t)DM * NH * DH * 2));
    u16* w1_bf    = (u16*)(ws + alloc((size_t)DI * DM * 2));
    u16* w2_bf    = (u16*)(ws + alloc((size_t)DM * DI * 2));
    u16* r_bf     = (u16*)(ws + alloc((size_t)KL * DM * 2));
    float* rb2    = (float*)(ws + alloc((size_t)NH * KL * 4));
    u16* Wh_bf    = (u16*)(ws + alloc((size_t)KL * BATCH * 3072 * 2));
    u16* av_bf    = (u16*)(ws + alloc((size_t)QL * BATCH * DM * 2));
    float* ao_f   = (float*)(ws + alloc((size_t)QL * BATCH * DM * 4));
    float* h_f    = (float*)(ws + alloc((size_t)QL * BATCH * DM * 4));
    u16* h_bf     = (u16*)(ws + alloc((size_t)QL * BATCH * DM * 2));
    u16* inner_bf = (u16*)(ws + alloc((size_t)QL * BATCH * DI * 2));
    float* ffo_f  = (float*)(ws + alloc((size_t)QL * BATCH * DM * 4));
    (void)ws_size; (void)in_sizes; (void)n_in; (void)out_size;

    // 1) conversions + rel-bias prep
    cvt_f2b<<<1024, 256, 0, stream>>>(mems, cat_bf, MLN * BATCH * DM);
    cvt_f2b<<<1024, 256, 0, stream>>>(w, cat_bf + (size_t)MLN * BATCH * DM, QL * BATCH * DM);
    cvt_f2b<<<1024, 256, 0, stream>>>(qkv_w, qkvw_bf, 3 * NH * DH * DM);
    cvt_f2b<<<512, 256, 0, stream>>>(o_w, ow_bf, DM * NH * DH);
    cvt_f2b<<<1024, 256, 0, stream>>>(ff_w1, w1_bf, DI * DM);
    cvt_f2b<<<1024, 256, 0, stream>>>(ff_w2, w2_bf, DM * DI);
    cvt_f2b<<<1024, 256, 0, stream>>>(r_emb, r_bf, KL * DM);
    rb2_prep<<<(NH * KL + 255) / 256, 256, 0, stream>>>(r_emb, r_w_bias, r_bias, rb2);

    // 2) QKV projection
    gemm_bt<1><<<dim3(3072 / 128, (KL * BATCH) / 128), 256, 0, stream>>>(
        cat_bf, qkvw_bf, nullptr, Wh_bf, nullptr, KL * BATCH, 3072, DM);

    // 3) flash attention
    flash_attn<<<dim3(QL / 64, BATCH * NH), 256, 0, stream>>>(Wh_bf, r_bf, r_w_bias,
                                                              rb2, av_bf);

    // 4) output projection
    gemm_bt<0><<<dim3(DM / 128, (QL * BATCH) / 128), 256, 0, stream>>>(
        av_bf, ow_bf, ao_f, nullptr, nullptr, QL * BATCH, DM, DM);

    // 5) h = LN(w + attn_out)
    ln_fused<<<QL * BATCH, 256, 0, stream>>>(w, ao_f, ln1_g, ln1_b, h_f, h_bf, 3);

    // 6) inner = relu(h * ff_w1^T + b1)
    gemm_bt<1 | 2 | 4><<<dim3(DI / 128, (QL * BATCH) / 128), 256, 0, stream>>>(
        h_bf, w1_bf, nullptr, inner_bf, ff_b1, QL * BATCH, DI, DM);

    // 7) ff_out = inner * ff_w2^T + b2
    gemm_bt<2><<<dim3(DM / 128, (QL * BATCH) / 128), 256, 0, stream>>>(
        inner_bf, w2_bf, ffo_f, nullptr, ff_b2, QL * BATCH, DM, DI);

    // 8) out = LN(h + ff_out)
    ln_fused<<<QL * BATCH, 256, 0, stream>>>(h_f, ffo_f, ln2_g, ln2_b, out, nullptr, 1);
}